// Round 7
// baseline (284.297 us; speedup 1.0000x reference)
//
#include <hip/hip_runtime.h>

// Problem constants
#define B_  4
#define T_  2048
#define E_  1024
#define H_  16
#define D_  64
#define HD_ 1024   // H_*D_
#define BT_ 8192   // B_*T_

typedef __bf16 bf16x8 __attribute__((ext_vector_type(8)));
typedef float  f32x4  __attribute__((ext_vector_type(4)));

// native f32->bf16 (RNE)
static __device__ __forceinline__ unsigned short f2bf(float f) {
  __bf16 h = (__bf16)f;
  return __builtin_bit_cast(unsigned short, h);
}
static __device__ __forceinline__ bf16x8 ldb8(const unsigned short* p) {
  return *(const bf16x8*)p;
}

// async global->LDS, 16B per lane; LDS dest = wave-uniform base + lane*16
#define GLD_LDS16(gp, lp)                                                      \
  __builtin_amdgcn_global_load_lds(                                            \
      (const __attribute__((address_space(1))) void*)(gp),                     \
      (__attribute__((address_space(3))) void*)(lp), 16, 0, 0)

// ---------------- fused prep: x cast + weight transpose-casts ----------------
// (byte-identical to R6's passing version)
__global__ __launch_bounds__(256) void prep_k(const float* __restrict__ x,
                                              const float* __restrict__ Wq,
                                              const float* __restrict__ Wk,
                                              const float* __restrict__ Wv,
                                              const float* __restrict__ Wo,
                                              unsigned short* __restrict__ xb,
                                              unsigned short* __restrict__ wT,
                                              unsigned short* __restrict__ woT) {
  const int bid = blockIdx.x, tid = threadIdx.x;
  if (bid < 2048) {                            // ---- x cast ----
    #pragma unroll
    for (int p = 0; p < 4; ++p) {
      int i = bid * 1024 + p * 256 + tid;      // float4 index
      float4 v = ((const float4*)x)[i];
      ushort4 o;
      o.x = f2bf(v.x); o.y = f2bf(v.y); o.z = f2bf(v.z); o.w = f2bf(v.w);
      ((ushort4*)xb)[i] = o;
    }
    return;
  }
  __shared__ float tl[64 * 65];                // 64x64 tile, stride 65
  if (bid < 2816) {                            // ---- Wq/Wk/Wv transpose ----
    const int tix = bid - 2048;                // 0..767
    const int w = tix >> 8;                    // 0..2
    const int h = (tix >> 4) & 15;
    const int e0 = (tix & 15) * 64;
    const float* src = (w == 0) ? Wq : (w == 1) ? Wk : Wv;
    #pragma unroll
    for (int rr = 0; rr < 4; ++rr) {
      const int e = e0 + rr * 16 + (tid >> 4);
      const int d4 = (tid & 15) * 4;
      float4 v = *(const float4*)&src[(size_t)(h * 1024 + e) * 64 + d4];
      tl[(e - e0) * 65 + d4 + 0] = v.x;
      tl[(e - e0) * 65 + d4 + 1] = v.y;
      tl[(e - e0) * 65 + d4 + 2] = v.z;
      tl[(e - e0) * 65 + d4 + 3] = v.w;
    }
    __syncthreads();
    #pragma unroll
    for (int cc = 0; cc < 4; ++cc) {
      const int d = cc * 16 + (tid >> 4);
      const int e4 = (tid & 15) * 4;
      ushort4 o;
      o.x = f2bf(tl[(e4 + 0) * 65 + d]);
      o.y = f2bf(tl[(e4 + 1) * 65 + d]);
      o.z = f2bf(tl[(e4 + 2) * 65 + d]);
      o.w = f2bf(tl[(e4 + 3) * 65 + d]);
      *(ushort4*)&wT[(size_t)((w * 16 + h) * 64 + d) * 1024 + e0 + e4] = o;
    }
    return;
  }
  {                                            // ---- Wo transpose ----
    const int tix = bid - 2816;                // 0..255
    const int hd0 = (tix >> 4) * 64;
    const int e0 = (tix & 15) * 64;
    #pragma unroll
    for (int rr = 0; rr < 4; ++rr) {
      const int hd = hd0 + rr * 16 + (tid >> 4);
      const int e4 = (tid & 15) * 4;
      float4 v = *(const float4*)&Wo[(size_t)hd * 1024 + e0 + e4];
      tl[(hd - hd0) * 65 + e4 + 0] = v.x;
      tl[(hd - hd0) * 65 + e4 + 1] = v.y;
      tl[(hd - hd0) * 65 + e4 + 2] = v.z;
      tl[(hd - hd0) * 65 + e4 + 3] = v.w;
    }
    __syncthreads();
    #pragma unroll
    for (int cc = 0; cc < 4; ++cc) {
      const int e = e0 + cc * 16 + (tid >> 4);
      const int hd4 = (tid & 15) * 4;
      ushort4 o;
      o.x = f2bf(tl[(hd4 + 0) * 65 + (e - e0)]);
      o.y = f2bf(tl[(hd4 + 1) * 65 + (e - e0)]);
      o.z = f2bf(tl[(hd4 + 2) * 65 + (e - e0)]);
      o.w = f2bf(tl[(hd4 + 3) * 65 + (e - e0)]);
      *(ushort4*)&woT[(size_t)e * 1024 + hd0 + hd4] = o;
    }
  }
}

// ------------- 128x64 GEMM core: BK=32, dbuf, 24KB LDS, high-TLP ------------
// GUIDELINE-1 redesign: tile halved (128M x 64N) so the grid provides 6
// blocks/CU (qkv) / 4 (proj); ~5 co-resident desynchronized barrier groups
// hide each other's staging latency (the schedule-invariant ~2300cyc/iter
// wall of R1/R2/R3/R6 was exposed load latency at 2-3 lockstep blocks/CU).
// 4 waves: wave tile 64x32 (wm=wave&1 M-half, wn=wave>>1 N-half), acc[4][2].
// Conflict-free LDS (proven 0-conflict in R6, rederived for 64B rows):
// physical slot = logical_quad ^ ((row>>1)&3) -> 16 lanes spread over all 8
// bank-groups, 2-way aliasing only (free per m136). Writer pre-swizzles the
// global source column so global_load_lds dest stays linear (both-sides rule).
// Buffer strides in USHORTS: lA buf = 4096 (128x32), lB buf = 2048 (64x32).
static __device__ __forceinline__ void gemm_core(const unsigned short* __restrict__ A,
                                                 const unsigned short* __restrict__ BT,
                                                 const int K, const int m0, const int n0,
                                                 unsigned short* lA, unsigned short* lB,
                                                 f32x4 acc[4][2]) {
  const int tid  = threadIdx.x;
  const int wave = tid >> 6;
  const int lane = tid & 63;
  const int wm = wave & 1, wn = wave >> 1;
  const int l16 = lane & 15, quad = lane >> 4;
  const int nit = K >> 5;                      // K-steps of 32 (=32 here)

  // staging map: thread t covers (row = t>>2, slot = t&3) of a 64-row group
  const int sr = tid >> 2;                     // 0..63
  const int sc = ((tid & 3) ^ ((sr >> 1) & 3)) * 8;  // pre-swizzled src col
  // reader: physical slot for logical slot `quad` at row stripe l16
  const int slot = (quad ^ ((l16 >> 1) & 3)) << 3;   // ushorts

#define STG(kt) do {                                                            \
    const size_t kb = (size_t)(kt) * 32 + sc;                                   \
    unsigned short* dA = lA + ((kt) & 1) * 4096 + wave * 512;                   \
    unsigned short* dB = lB + ((kt) & 1) * 2048 + wave * 512;                   \
    GLD_LDS16(A  + (size_t)(m0 +      sr) * K + kb, dA);                        \
    GLD_LDS16(A  + (size_t)(m0 + 64 + sr) * K + kb, dA + 2048);                 \
    GLD_LDS16(BT + (size_t)(n0 +      sr) * K + kb, dB);                        \
  } while (0)

  #pragma unroll
  for (int i = 0; i < 4; ++i)
    #pragma unroll
    for (int j = 0; j < 2; ++j) acc[i][j] = (f32x4){0.f, 0.f, 0.f, 0.f};

  STG(0);                                      // prologue
  for (int kt = 0; kt < nit; ++kt) {
    __syncthreads();                           // buf[kt&1] staged; prev reads done
    if (kt + 1 < nit) STG(kt + 1);             // prefetch; drains at next barrier
    const unsigned short* cA = lA + (kt & 1) * 4096;
    const unsigned short* cB = lB + (kt & 1) * 2048;
    bf16x8 aF[4], bF[2];
    #pragma unroll
    for (int mi = 0; mi < 4; ++mi)
      aF[mi] = ldb8(cA + (wm * 64 + mi * 16 + l16) * 32 + slot);
    #pragma unroll
    for (int nj = 0; nj < 2; ++nj)
      bF[nj] = ldb8(cB + (wn * 32 + nj * 16 + l16) * 32 + slot);
    __builtin_amdgcn_s_setprio(1);
    #pragma unroll
    for (int mi = 0; mi < 4; ++mi)
      #pragma unroll
      for (int nj = 0; nj < 2; ++nj)
        acc[mi][nj] = __builtin_amdgcn_mfma_f32_16x16x32_bf16(aF[mi], bF[nj],
                                                              acc[mi][nj], 0, 0, 0);
    __builtin_amdgcn_s_setprio(0);
  }
#undef STG
}

// QKV: x[8192,1024] @ wT[3072,1024]^T; scatter epilogue to q/k/vT.
// q is PRE-SCALED by 0.125*log2(e) so attn can use exp2 directly.
__global__ __launch_bounds__(256) void qkv_gemm_k(const unsigned short* __restrict__ xb,
                                                  const unsigned short* __restrict__ wT,
                                                  unsigned short* __restrict__ q,
                                                  unsigned short* __restrict__ k,
                                                  unsigned short* __restrict__ vT) {
  __shared__ unsigned short lA[2 * 128 * 32];  // 16 KB
  __shared__ unsigned short lB[2 * 64 * 32];   //  8 KB
  f32x4 acc[4][2];
  const int m0 = blockIdx.x * 128, n0 = blockIdx.y * 64;
  gemm_core(xb, wT, E_, m0, n0, lA, lB, acc);

  const int wave = threadIdx.x >> 6, lane = threadIdx.x & 63;
  const int wm = wave & 1, wn = wave >> 1;
  const int l16 = lane & 15, quad = lane >> 4;
  const int type = n0 >> 10;                   // block-uniform (64-aligned tiles)
  const float C = 0.18033688011112042f;        // 0.125 * log2(e)
  #pragma unroll
  for (int i = 0; i < 4; ++i) {
    #pragma unroll
    for (int j = 0; j < 2; ++j) {
      const int n = n0 + wn * 32 + j * 16 + l16;
      const int h = (n >> 6) & 15, d = n & 63;
      #pragma unroll
      for (int r = 0; r < 4; ++r) {
        const int m = m0 + wm * 64 + i * 16 + quad * 4 + r;
        const int b = m >> 11, t = m & (T_ - 1);
        if (type == 0)
          q[((size_t)(b * H_ + h) * T_ + t) * D_ + d] = f2bf(acc[i][j][r] * C);
        else if (type == 1)
          k[((size_t)(b * H_ + h) * T_ + t) * D_ + d] = f2bf(acc[i][j][r]);
        else
          vT[((size_t)(b * H_ + h) * D_ + d) * T_ + t] = f2bf(acc[i][j][r]);
      }
    }
  }
}

// proj: ao[8192,1024] @ woT[1024,1024]^T -> out fp32
__global__ __launch_bounds__(256) void proj_k(const unsigned short* __restrict__ ao,
                                              const unsigned short* __restrict__ woT,
                                              float* __restrict__ out) {
  __shared__ unsigned short lA[2 * 128 * 32];
  __shared__ unsigned short lB[2 * 64 * 32];
  f32x4 acc[4][2];
  const int m0 = blockIdx.x * 128, n0 = blockIdx.y * 64;
  gemm_core(ao, woT, HD_, m0, n0, lA, lB, acc);

  const int wave = threadIdx.x >> 6, lane = threadIdx.x & 63;
  const int wm = wave & 1, wn = wave >> 1;
  const int l16 = lane & 15, quad = lane >> 4;
  #pragma unroll
  for (int i = 0; i < 4; ++i)
    #pragma unroll
    for (int j = 0; j < 2; ++j)
      #pragma unroll
      for (int r = 0; r < 4; ++r)
        out[(size_t)(m0 + wm * 64 + i * 16 + quad * 4 + r) * E_ +
            n0 + wn * 32 + j * 16 + l16] = acc[i][j][r];
}

// ------------- flash attention (causal, dbuf LDS staging, XCD-local) ---------
// EXACT R2/R6 version (passed three times).
__global__ __launch_bounds__(256) void attn_k(const unsigned short* __restrict__ q,
                                              const unsigned short* __restrict__ k,
                                              const unsigned short* __restrict__ vT,
                                              unsigned short* __restrict__ ao) {
  __shared__ unsigned short lK[2][64 * 64];    // [s][d] seg-swizzled, 2 x 8 KB
  __shared__ unsigned short lV[2][64 * 64];    // [d][s] seg-swizzled, 2 x 8 KB
  __shared__ unsigned short lP[4][32][72];     // per-wave P tiles, padded, 18 KB
  const int tid  = threadIdx.x;
  const int lane = tid & 63;
  const int wave = tid >> 6;
  const int l16  = lane & 15;
  const int quad = lane >> 4;
  const int id    = (int)blockIdx.x;           // 0..511
  const int bhid  = id & 63;                   // same bh -> same id%8 -> same XCD
  const int qpair = id >> 6;                   // 0..7
  const int h = bhid & 15, b = bhid >> 4;
  const size_t bh = (size_t)(b * H_ + h);
  const unsigned short* qp = q  + bh * (T_ * D_);
  const unsigned short* kp = k  + bh * (T_ * D_);
  const unsigned short* vp = vT + bh * (D_ * T_);

  // staging: slot t -> (row = t/8, seg = t%8) of a 64-row x 128B tile half
  const int srow = tid >> 3;
  const int kseg = (tid & 7) ^ (srow & 7);     // XOR swizzle
  const int sw = (l16 & 7);                    // reader-side swizzle key

  #pragma unroll
  for (int pr = 0; pr < 2; ++pr) {
    const int qblk = (pr == 0) ? qpair : 15 - qpair;
    const int q0 = qblk * 128 + wave * 32;     // this wave's first q-row

    bf16x8 aq[2][2];
    #pragma unroll
    for (int rb = 0; rb < 2; ++rb)
      #pragma unroll
      for (int hh = 0; hh < 2; ++hh)
        aq[rb][hh] = ldb8(qp + (q0 + rb * 16 + l16) * D_ + hh * 32 + quad * 8);

    float lr[2][4];
    f32x4 o[2][4];
    #pragma unroll
    for (int rb = 0; rb < 2; ++rb) {
      #pragma unroll
      for (int r = 0; r < 4; ++r) lr[rb][r] = 0.f;
      #pragma unroll
      for (int nb = 0; nb < 4; ++nb) o[rb][nb] = (f32x4){0.f, 0.f, 0.f, 0.f};
    }

    const int nch = 2 * (qblk + 1);            // even

    // prologue: stage chunk 0 into buf 0
    {
      unsigned short* Kb = lK[0];
      unsigned short* Vb = lV[0];
      GLD_LDS16(kp + srow * D_ + kseg * 8, Kb + wave * 512);
      GLD_LDS16(kp + (32 + srow) * D_ + kseg * 8, Kb + 2048 + wave * 512);
      GLD_LDS16(vp + (size_t)srow * T_ + kseg * 8, Vb + wave * 512);
      GLD_LDS16(vp + (size_t)(32 + srow) * T_ + kseg * 8, Vb + 2048 + wave * 512);
    }

    for (int c = 0; c < nch; ++c) {
      __syncthreads();                         // buf[c&1] staged; prev compute done
      if (c + 1 < nch) {                       // prefetch next chunk into other buf
        const int s1 = (c + 1) * 64;
        unsigned short* Kb = lK[(c + 1) & 1];
        unsigned short* Vb = lV[(c + 1) & 1];
        GLD_LDS16(kp + (s1 + srow) * D_ + kseg * 8, Kb + wave * 512);
        GLD_LDS16(kp + (s1 + 32 + srow) * D_ + kseg * 8, Kb + 2048 + wave * 512);
        GLD_LDS16(vp + (size_t)srow * T_ + s1 + kseg * 8, Vb + wave * 512);
        GLD_LDS16(vp + (size_t)(32 + srow) * T_ + s1 + kseg * 8, Vb + 2048 + wave * 512);
      }
      const int s0 = c * 64;
      const unsigned short* Kb = lK[c & 1];
      const unsigned short* Vb = lV[c & 1];
      // ---- QK^T ----
      f32x4 sc[2][4];
      #pragma unroll
      for (int rb = 0; rb < 2; ++rb)
        #pragma unroll
        for (int j = 0; j < 4; ++j) sc[rb][j] = (f32x4){0.f, 0.f, 0.f, 0.f};
      #pragma unroll
      for (int j = 0; j < 4; ++j) {
        const int sr = j * 16 + l16;
        bf16x8 bk0 = ldb8(Kb + sr * 64 + ((quad ^ sw) << 3));
        bf16x8 bk1 = ldb8(Kb + sr * 64 + (((4 + quad) ^ sw) << 3));
        #pragma unroll
        for (int rb = 0; rb < 2; ++rb) {
          sc[rb][j] = __builtin_amdgcn_mfma_f32_16x16x32_bf16(aq[rb][0], bk0, sc[rb][j], 0, 0, 0);
          sc[rb][j] = __builtin_amdgcn_mfma_f32_16x16x32_bf16(aq[rb][1], bk1, sc[rb][j], 0, 0, 0);
        }
      }
      // ---- exp2 (+ causal mask on the diagonal chunk) + P write ----
      const bool domask = (c == nch - 1) || (c == nch - 2);  // s0+63 > q0 region
      #pragma unroll
      for (int rb = 0; rb < 2; ++rb) {
        #pragma unroll
        for (int j = 0; j < 4; ++j) {
          #pragma unroll
          for (int r = 0; r < 4; ++r) {
            float p = __builtin_amdgcn_exp2f(sc[rb][j][r]);
            if (domask) {
              const int qg = q0 + rb * 16 + quad * 4 + r;
              if (s0 + j * 16 + l16 > qg) p = 0.f;
            }
            lr[rb][r] += p;
            lP[wave][rb * 16 + quad * 4 + r][j * 16 + l16] = f2bf(p);
          }
        }
      }
      __builtin_amdgcn_wave_barrier();
      bf16x8 aP[2][2];
      #pragma unroll
      for (int rb = 0; rb < 2; ++rb)
        #pragma unroll
        for (int hh = 0; hh < 2; ++hh)
          aP[rb][hh] = ldb8(&lP[wave][rb * 16 + l16][hh * 32 + quad * 8]);
      __builtin_amdgcn_wave_barrier();
      // ---- PV ----
      #pragma unroll
      for (int nb = 0; nb < 4; ++nb) {
        const int d = nb * 16 + l16;
        bf16x8 bV0 = ldb8(Vb + d * 64 + ((quad ^ sw) << 3));
        bf16x8 bV1 = ldb8(Vb + d * 64 + (((4 + quad) ^ sw) << 3));
        #pragma unroll
        for (int rb = 0; rb < 2; ++rb) {
          o[rb][nb] = __builtin_amdgcn_mfma_f32_16x16x32_bf16(aP[rb][0], bV0, o[rb][nb], 0, 0, 0);
          o[rb][nb] = __builtin_amdgcn_mfma_f32_16x16x32_bf16(aP[rb][1], bV1, o[rb][nb], 0, 0, 0);
        }
      }
    }

    // epilogue: row-sum reduction across the 16 l16 lanes, normalize, store
    #pragma unroll
    for (int off = 1; off < 16; off <<= 1)
      #pragma unroll
      for (int rb = 0; rb < 2; ++rb)
        #pragma unroll
        for (int r = 0; r < 4; ++r)
          lr[rb][r] += __shfl_xor(lr[rb][r], off, 64);
    #pragma unroll
    for (int rb = 0; rb < 2; ++rb) {
      #pragma unroll
      for (int r = 0; r < 4; ++r) {
        const float inv = 1.0f / lr[rb][r];
        const int t = q0 + rb * 16 + quad * 4 + r;
        #pragma unroll
        for (int nb = 0; nb < 4; ++nb)
          ao[((size_t)(b * T_ + t) * H_ + h) * D_ + nb * 16 + l16] = f2bf(o[rb][nb][r] * inv);
      }
    }
  }
}

// ---------------- launch ----------------

extern "C" void kernel_launch(void* const* d_in, const int* in_sizes, int n_in,
                              void* d_out, int out_size, void* d_ws, size_t ws_size,
                              hipStream_t stream) {
  const float* x  = (const float*)d_in[0];
  const float* Wq = (const float*)d_in[1];
  const float* Wk = (const float*)d_in[2];
  const float* Wv = (const float*)d_in[3];
  const float* Wo = (const float*)d_in[4];
  float* out = (float*)d_out;

  char* ws = (char*)d_ws;
  unsigned short* xb   = (unsigned short*)(ws + 0);          // 16 MiB: x bf16 [8192,1024]
  unsigned short* wT   = (unsigned short*)(ws + 16777216);   //  6 MiB: [3,H,D,E] bf16
  unsigned short* woT  = (unsigned short*)(ws + 23068672);   //  2 MiB: [E,HD] bf16
  unsigned short* qb   = (unsigned short*)(ws + 25165824);   // 16 MiB: q [B,H,T,D] (pre-scaled)
  unsigned short* kb   = (unsigned short*)(ws + 41943040);   // 16 MiB: k [B,H,T,D]
  unsigned short* vTb  = (unsigned short*)(ws + 58720256);   // 16 MiB: v^T [B,H,D,T]
  unsigned short* aob  = (unsigned short*)(ws + 75497472);   // 16 MiB: attn out [B,T,H,D]
  // total: 92,274,688 bytes

  prep_k<<<dim3(3072), dim3(256), 0, stream>>>(x, Wq, Wk, Wv, Wo, xb, wT, woT);
  qkv_gemm_k<<<dim3(BT_ / 128, 3072 / 64), dim3(256), 0, stream>>>(xb, wT, qb, kb, vTb);
  attn_k<<<dim3(512), dim3(256), 0, stream>>>(qb, kb, vTb, aob);
  proj_k<<<dim3(BT_ / 128, E_ / 64), dim3(256), 0, stream>>>(aob, woT, out);
}

// Round 8
// 257.091 us; speedup vs baseline: 1.1058x; 1.1058x over previous
//
#include <hip/hip_runtime.h>

// Problem constants
#define B_  4
#define T_  2048
#define E_  1024
#define H_  16
#define D_  64
#define HD_ 1024   // H_*D_
#define BT_ 8192   // B_*T_

typedef __bf16 bf16x8 __attribute__((ext_vector_type(8)));
typedef float  f32x4  __attribute__((ext_vector_type(4)));

// native f32->bf16 (RNE)
static __device__ __forceinline__ unsigned short f2bf(float f) {
  __bf16 h = (__bf16)f;
  return __builtin_bit_cast(unsigned short, h);
}
static __device__ __forceinline__ bf16x8 ldb8(const unsigned short* p) {
  return *(const bf16x8*)p;
}

// async global->LDS, 16B per lane; LDS dest = wave-uniform base + lane*16
#define GLD_LDS16(gp, lp)                                                      \
  __builtin_amdgcn_global_load_lds(                                            \
      (const __attribute__((address_space(1))) void*)(gp),                     \
      (__attribute__((address_space(3))) void*)(lp), 16, 0, 0)

// ---------------- fused prep: x cast + weight transpose-casts ----------------
// (byte-identical to R6's passing version)
__global__ __launch_bounds__(256) void prep_k(const float* __restrict__ x,
                                              const float* __restrict__ Wq,
                                              const float* __restrict__ Wk,
                                              const float* __restrict__ Wv,
                                              const float* __restrict__ Wo,
                                              unsigned short* __restrict__ xb,
                                              unsigned short* __restrict__ wT,
                                              unsigned short* __restrict__ woT) {
  const int bid = blockIdx.x, tid = threadIdx.x;
  if (bid < 2048) {                            // ---- x cast ----
    #pragma unroll
    for (int p = 0; p < 4; ++p) {
      int i = bid * 1024 + p * 256 + tid;      // float4 index
      float4 v = ((const float4*)x)[i];
      ushort4 o;
      o.x = f2bf(v.x); o.y = f2bf(v.y); o.z = f2bf(v.z); o.w = f2bf(v.w);
      ((ushort4*)xb)[i] = o;
    }
    return;
  }
  __shared__ float tl[64 * 65];                // 64x64 tile, stride 65
  if (bid < 2816) {                            // ---- Wq/Wk/Wv transpose ----
    const int tix = bid - 2048;                // 0..767
    const int w = tix >> 8;                    // 0..2
    const int h = (tix >> 4) & 15;
    const int e0 = (tix & 15) * 64;
    const float* src = (w == 0) ? Wq : (w == 1) ? Wk : Wv;
    #pragma unroll
    for (int rr = 0; rr < 4; ++rr) {
      const int e = e0 + rr * 16 + (tid >> 4);
      const int d4 = (tid & 15) * 4;
      float4 v = *(const float4*)&src[(size_t)(h * 1024 + e) * 64 + d4];
      tl[(e - e0) * 65 + d4 + 0] = v.x;
      tl[(e - e0) * 65 + d4 + 1] = v.y;
      tl[(e - e0) * 65 + d4 + 2] = v.z;
      tl[(e - e0) * 65 + d4 + 3] = v.w;
    }
    __syncthreads();
    #pragma unroll
    for (int cc = 0; cc < 4; ++cc) {
      const int d = cc * 16 + (tid >> 4);
      const int e4 = (tid & 15) * 4;
      ushort4 o;
      o.x = f2bf(tl[(e4 + 0) * 65 + d]);
      o.y = f2bf(tl[(e4 + 1) * 65 + d]);
      o.z = f2bf(tl[(e4 + 2) * 65 + d]);
      o.w = f2bf(tl[(e4 + 3) * 65 + d]);
      *(ushort4*)&wT[(size_t)((w * 16 + h) * 64 + d) * 1024 + e0 + e4] = o;
    }
    return;
  }
  {                                            // ---- Wo transpose ----
    const int tix = bid - 2816;                // 0..255
    const int hd0 = (tix >> 4) * 64;
    const int e0 = (tix & 15) * 64;
    #pragma unroll
    for (int rr = 0; rr < 4; ++rr) {
      const int hd = hd0 + rr * 16 + (tid >> 4);
      const int e4 = (tid & 15) * 4;
      float4 v = *(const float4*)&Wo[(size_t)hd * 1024 + e0 + e4];
      tl[(hd - hd0) * 65 + e4 + 0] = v.x;
      tl[(hd - hd0) * 65 + e4 + 1] = v.y;
      tl[(hd - hd0) * 65 + e4 + 2] = v.z;
      tl[(hd - hd0) * 65 + e4 + 3] = v.w;
    }
    __syncthreads();
    #pragma unroll
    for (int cc = 0; cc < 4; ++cc) {
      const int e = e0 + cc * 16 + (tid >> 4);
      const int hd4 = (tid & 15) * 4;
      ushort4 o;
      o.x = f2bf(tl[(hd4 + 0) * 65 + (e - e0)]);
      o.y = f2bf(tl[(hd4 + 1) * 65 + (e - e0)]);
      o.z = f2bf(tl[(hd4 + 2) * 65 + (e - e0)]);
      o.w = f2bf(tl[(hd4 + 3) * 65 + (e - e0)]);
      *(ushort4*)&woT[(size_t)e * 1024 + hd0 + hd4] = o;
    }
  }
}

// ------------- 128x128 GEMM core: R2 schedule + R7 conflict-free layout -----
// Schedule = R2's exact (best measured, 91us): 3-buffer ring, depth-2
// prefetch, counted vmcnt(4) so staging loads span a full compute iter across
// raw s_barrier (never drain to 0 mid-loop). Layout = R7's measured-0-conflict
// 64B rows: phys slot = quad ^ ((row>>1)&3) (2-way bank aliasing = free,
// m136); writer pre-swizzles the global source column so global_load_lds dest
// stays linear (both-sides rule). Buffer stride 4096 USHORTS (128x32 = 8KB).
// LDS 48 KB -> 3 blocks/CU.
static __device__ __forceinline__ void gemm_core(const unsigned short* __restrict__ A,
                                                 const unsigned short* __restrict__ BT,
                                                 const int K, const int m0, const int n0,
                                                 unsigned short* lA, unsigned short* lB,
                                                 f32x4 acc[4][4]) {
  const int tid  = threadIdx.x;
  const int wave = tid >> 6;
  const int lane = tid & 63;
  const int wm = wave & 1, wn = wave >> 1;
  const int l16 = lane & 15, quad = lane >> 4;
  const int nit = K >> 5;                      // K-steps of 32 (>= 3)

  // staging: thread t -> row sr = t>>2 (0..63), slot t&3; src col pre-swizzled
  const int sr = tid >> 2;
  const int sc = ((tid & 3) ^ ((sr >> 1) & 3)) * 8;   // ushorts
  // reader: physical slot for logical slot `quad` at fragment row l16 (mod 16)
  const int slot = (quad ^ ((l16 >> 1) & 3)) << 3;    // ushorts

#define STG(kt, bi) do {                                                        \
    const size_t kb = (size_t)(kt) * 32 + sc;                                   \
    unsigned short* dA = lA + (bi) * 4096 + wave * 512;                         \
    unsigned short* dB = lB + (bi) * 4096 + wave * 512;                         \
    GLD_LDS16(A  + (size_t)(m0 +      sr) * K + kb, dA);                        \
    GLD_LDS16(A  + (size_t)(m0 + 64 + sr) * K + kb, dA + 2048);                 \
    GLD_LDS16(BT + (size_t)(n0 +      sr) * K + kb, dB);                        \
    GLD_LDS16(BT + (size_t)(n0 + 64 + sr) * K + kb, dB + 2048);                 \
  } while (0)

  #pragma unroll
  for (int i = 0; i < 4; ++i)
    #pragma unroll
    for (int j = 0; j < 4; ++j) acc[i][j] = (f32x4){0.f, 0.f, 0.f, 0.f};

  // prologue: stage iters 0,1 into bufs 0,1
  STG(0, 0);
  STG(1, 1);
  asm volatile("s_waitcnt vmcnt(4)" ::: "memory");   // S(0) landed, S(1) in flight
  __builtin_amdgcn_s_barrier();

  int cb = 0, sb = 2;                          // current buf, stage buf (t+2)%3
  for (int it = 0; it < nit; ++it) {
    if (it + 2 < nit) STG(it + 2, sb);         // depth-2 prefetch
    const unsigned short* cA = lA + cb * 4096;
    const unsigned short* cB = lB + cb * 4096;
    bf16x8 aF[4], bF[4];
    #pragma unroll
    for (int mi = 0; mi < 4; ++mi)
      aF[mi] = ldb8(cA + (wm * 64 + mi * 16 + l16) * 32 + slot);
    #pragma unroll
    for (int nj = 0; nj < 4; ++nj)
      bF[nj] = ldb8(cB + (wn * 64 + nj * 16 + l16) * 32 + slot);
    __builtin_amdgcn_s_setprio(1);
    #pragma unroll
    for (int mi = 0; mi < 4; ++mi)
      #pragma unroll
      for (int nj = 0; nj < 4; ++nj)
        acc[mi][nj] = __builtin_amdgcn_mfma_f32_16x16x32_bf16(aF[mi], bF[nj],
                                                              acc[mi][nj], 0, 0, 0);
    __builtin_amdgcn_s_setprio(0);
    if (it + 1 < nit) {
      if (it + 2 < nit)
        asm volatile("s_waitcnt vmcnt(4)" ::: "memory");  // S(t+1) done
      else
        asm volatile("s_waitcnt vmcnt(0)" ::: "memory");  // tail drain
      __builtin_amdgcn_s_barrier();
    }
    cb = (cb == 2) ? 0 : cb + 1;
    sb = (sb == 2) ? 0 : sb + 1;
  }
#undef STG
}

// QKV: x[8192,1024] @ wT[3072,1024]^T; scatter epilogue to q/k/vT.
// q is PRE-SCALED by 0.125*log2(e) so attn can use exp2 directly.
__global__ __launch_bounds__(256) void qkv_gemm_k(const unsigned short* __restrict__ xb,
                                                  const unsigned short* __restrict__ wT,
                                                  unsigned short* __restrict__ q,
                                                  unsigned short* __restrict__ k,
                                                  unsigned short* __restrict__ vT) {
  __shared__ unsigned short lA[3 * 128 * 32], lB[3 * 128 * 32];  // 48 KB
  f32x4 acc[4][4];
  const int m0 = blockIdx.x * 128, n0 = blockIdx.y * 128;
  gemm_core(xb, wT, E_, m0, n0, lA, lB, acc);

  const int wave = threadIdx.x >> 6, lane = threadIdx.x & 63;
  const int wm = wave & 1, wn = wave >> 1;
  const int l16 = lane & 15, quad = lane >> 4;
  const int type = n0 >> 10;                   // block-uniform
  const float C = 0.18033688011112042f;        // 0.125 * log2(e)
  #pragma unroll
  for (int i = 0; i < 4; ++i) {
    #pragma unroll
    for (int j = 0; j < 4; ++j) {
      const int n = n0 + wn * 64 + j * 16 + l16;
      const int h = (n >> 6) & 15, d = n & 63;
      #pragma unroll
      for (int r = 0; r < 4; ++r) {
        const int m = m0 + wm * 64 + i * 16 + quad * 4 + r;
        const int b = m >> 11, t = m & (T_ - 1);
        if (type == 0)
          q[((size_t)(b * H_ + h) * T_ + t) * D_ + d] = f2bf(acc[i][j][r] * C);
        else if (type == 1)
          k[((size_t)(b * H_ + h) * T_ + t) * D_ + d] = f2bf(acc[i][j][r]);
        else
          vT[((size_t)(b * H_ + h) * D_ + d) * T_ + t] = f2bf(acc[i][j][r]);
      }
    }
  }
}

// proj: ao[8192,1024] @ woT[1024,1024]^T -> out fp32
__global__ __launch_bounds__(256) void proj_k(const unsigned short* __restrict__ ao,
                                              const unsigned short* __restrict__ woT,
                                              float* __restrict__ out) {
  __shared__ unsigned short lA[3 * 128 * 32], lB[3 * 128 * 32];
  f32x4 acc[4][4];
  const int m0 = blockIdx.x * 128, n0 = blockIdx.y * 128;
  gemm_core(ao, woT, HD_, m0, n0, lA, lB, acc);

  const int wave = threadIdx.x >> 6, lane = threadIdx.x & 63;
  const int wm = wave & 1, wn = wave >> 1;
  const int l16 = lane & 15, quad = lane >> 4;
  #pragma unroll
  for (int i = 0; i < 4; ++i)
    #pragma unroll
    for (int j = 0; j < 4; ++j)
      #pragma unroll
      for (int r = 0; r < 4; ++r)
        out[(size_t)(m0 + wm * 64 + i * 16 + quad * 4 + r) * E_ +
            n0 + wn * 64 + j * 16 + l16] = acc[i][j][r];
}

// ------------- flash attention (causal, ring-3 counted-vmcnt, XCD-local) ----
// R4's ring-3 version (exonerated: R4/R5's NaN was the GEMM ushort-stride
// bug). Counted vmcnt(4): chunk c+1's loads (issued at iter c-1) get a full
// chunk of compute in flight; raw s_barrier, no mid-loop drain to 0.
__global__ __launch_bounds__(256) void attn_k(const unsigned short* __restrict__ q,
                                              const unsigned short* __restrict__ k,
                                              const unsigned short* __restrict__ vT,
                                              unsigned short* __restrict__ ao) {
  __shared__ unsigned short lK[3][64 * 64];    // [s][d] seg-swizzled, 3 x 8 KB
  __shared__ unsigned short lV[3][64 * 64];    // [d][s] seg-swizzled, 3 x 8 KB
  __shared__ unsigned short lP[4][32][72];     // per-wave P tiles, padded, 18 KB
  const int tid  = threadIdx.x;
  const int lane = tid & 63;
  const int wave = tid >> 6;
  const int l16  = lane & 15;
  const int quad = lane >> 4;
  const int id    = (int)blockIdx.x;           // 0..511
  const int bhid  = id & 63;                   // same bh -> same id%8 -> same XCD
  const int qpair = id >> 6;                   // 0..7
  const int h = bhid & 15, b = bhid >> 4;
  const size_t bh = (size_t)(b * H_ + h);
  const unsigned short* qp = q  + bh * (T_ * D_);
  const unsigned short* kp = k  + bh * (T_ * D_);
  const unsigned short* vp = vT + bh * (D_ * T_);

  // staging: slot t -> (row = t/8, seg = t%8) of a 64-row x 128B tile half
  const int srow = tid >> 3;
  const int kseg = (tid & 7) ^ (srow & 7);     // XOR swizzle
  const int sw = (l16 & 7);                    // reader-side swizzle key

#define STAGE_CH(cc) do {                                                       \
    const int s1 = (cc) * 64;                                                   \
    unsigned short* Kb = lK[(cc) % 3];                                          \
    unsigned short* Vb = lV[(cc) % 3];                                          \
    GLD_LDS16(kp + (s1 + srow) * D_ + kseg * 8, Kb + wave * 512);               \
    GLD_LDS16(kp + (s1 + 32 + srow) * D_ + kseg * 8, Kb + 2048 + wave * 512);   \
    GLD_LDS16(vp + (size_t)srow * T_ + s1 + kseg * 8, Vb + wave * 512);         \
    GLD_LDS16(vp + (size_t)(32 + srow) * T_ + s1 + kseg * 8, Vb + 2048 + wave * 512); \
  } while (0)

  #pragma unroll
  for (int pr = 0; pr < 2; ++pr) {
    const int qblk = (pr == 0) ? qpair : 15 - qpair;
    const int q0 = qblk * 128 + wave * 32;     // this wave's first q-row

    __syncthreads();                           // buffers free before re-stage

    bf16x8 aq[2][2];
    #pragma unroll
    for (int rb = 0; rb < 2; ++rb)
      #pragma unroll
      for (int hh = 0; hh < 2; ++hh)
        aq[rb][hh] = ldb8(qp + (q0 + rb * 16 + l16) * D_ + hh * 32 + quad * 8);

    float lr[2][4];
    f32x4 o[2][4];
    #pragma unroll
    for (int rb = 0; rb < 2; ++rb) {
      #pragma unroll
      for (int r = 0; r < 4; ++r) lr[rb][r] = 0.f;
      #pragma unroll
      for (int nb = 0; nb < 4; ++nb) o[rb][nb] = (f32x4){0.f, 0.f, 0.f, 0.f};
    }

    const int nch = 2 * (qblk + 1);            // even, >= 2

    // prologue: stage chunks 0,1 into bufs 0,1; confirm chunk 0 landed
    STAGE_CH(0);
    STAGE_CH(1);
    asm volatile("s_waitcnt vmcnt(4)" ::: "memory");
    __builtin_amdgcn_s_barrier();
    asm volatile("" ::: "memory");

    for (int c = 0; c < nch; ++c) {
      if (c + 2 < nch) STAGE_CH(c + 2);        // buf last read at iter c-1
      const int s0 = c * 64;
      const unsigned short* Kb = lK[c % 3];
      const unsigned short* Vb = lV[c % 3];
      // ---- QK^T ----
      f32x4 sc[2][4];
      #pragma unroll
      for (int rb = 0; rb < 2; ++rb)
        #pragma unroll
        for (int j = 0; j < 4; ++j) sc[rb][j] = (f32x4){0.f, 0.f, 0.f, 0.f};
      #pragma unroll
      for (int j = 0; j < 4; ++j) {
        const int sr = j * 16 + l16;
        bf16x8 bk0 = ldb8(Kb + sr * 64 + ((quad ^ sw) << 3));
        bf16x8 bk1 = ldb8(Kb + sr * 64 + (((4 + quad) ^ sw) << 3));
        #pragma unroll
        for (int rb = 0; rb < 2; ++rb) {
          sc[rb][j] = __builtin_amdgcn_mfma_f32_16x16x32_bf16(aq[rb][0], bk0, sc[rb][j], 0, 0, 0);
          sc[rb][j] = __builtin_amdgcn_mfma_f32_16x16x32_bf16(aq[rb][1], bk1, sc[rb][j], 0, 0, 0);
        }
      }
      // ---- exp2 (+ causal mask on the diagonal chunk) + P write ----
      const bool domask = (c == nch - 1) || (c == nch - 2);
      #pragma unroll
      for (int rb = 0; rb < 2; ++rb) {
        #pragma unroll
        for (int j = 0; j < 4; ++j) {
          #pragma unroll
          for (int r = 0; r < 4; ++r) {
            float p = __builtin_amdgcn_exp2f(sc[rb][j][r]);
            if (domask) {
              const int qg = q0 + rb * 16 + quad * 4 + r;
              if (s0 + j * 16 + l16 > qg) p = 0.f;
            }
            lr[rb][r] += p;
            lP[wave][rb * 16 + quad * 4 + r][j * 16 + l16] = f2bf(p);
          }
        }
      }
      __builtin_amdgcn_wave_barrier();
      bf16x8 aP[2][2];
      #pragma unroll
      for (int rb = 0; rb < 2; ++rb)
        #pragma unroll
        for (int hh = 0; hh < 2; ++hh)
          aP[rb][hh] = ldb8(&lP[wave][rb * 16 + l16][hh * 32 + quad * 8]);
      __builtin_amdgcn_wave_barrier();
      // ---- PV ----
      #pragma unroll
      for (int nb = 0; nb < 4; ++nb) {
        const int d = nb * 16 + l16;
        bf16x8 bV0 = ldb8(Vb + d * 64 + ((quad ^ sw) << 3));
        bf16x8 bV1 = ldb8(Vb + d * 64 + (((4 + quad) ^ sw) << 3));
        #pragma unroll
        for (int rb = 0; rb < 2; ++rb) {
          o[rb][nb] = __builtin_amdgcn_mfma_f32_16x16x32_bf16(aP[rb][0], bV0, o[rb][nb], 0, 0, 0);
          o[rb][nb] = __builtin_amdgcn_mfma_f32_16x16x32_bf16(aP[rb][1], bV1, o[rb][nb], 0, 0, 0);
        }
      }
      // counted-vmcnt: confirm chunk c+1 landed (4 loads of c+2 stay in flight)
      if (c + 2 < nch)
        asm volatile("s_waitcnt vmcnt(4)" ::: "memory");
      else if (c + 1 < nch)
        asm volatile("s_waitcnt vmcnt(0)" ::: "memory");
      __builtin_amdgcn_s_barrier();
      asm volatile("" ::: "memory");
    }

    // epilogue: row-sum reduction across the 16 l16 lanes, normalize, store
    #pragma unroll
    for (int off = 1; off < 16; off <<= 1)
      #pragma unroll
      for (int rb = 0; rb < 2; ++rb)
        #pragma unroll
        for (int r = 0; r < 4; ++r)
          lr[rb][r] += __shfl_xor(lr[rb][r], off, 64);
    #pragma unroll
    for (int rb = 0; rb < 2; ++rb) {
      #pragma unroll
      for (int r = 0; r < 4; ++r) {
        const float inv = 1.0f / lr[rb][r];
        const int t = q0 + rb * 16 + quad * 4 + r;
        #pragma unroll
        for (int nb = 0; nb < 4; ++nb)
          ao[((size_t)(b * T_ + t) * H_ + h) * D_ + nb * 16 + l16] = f2bf(o[rb][nb][r] * inv);
      }
    }
  }
#undef STAGE_CH
}

// ---------------- launch ----------------

extern "C" void kernel_launch(void* const* d_in, const int* in_sizes, int n_in,
                              void* d_out, int out_size, void* d_ws, size_t ws_size,
                              hipStream_t stream) {
  const float* x  = (const float*)d_in[0];
  const float* Wq = (const float*)d_in[1];
  const float* Wk = (const float*)d_in[2];
  const float* Wv = (const float*)d_in[3];
  const float* Wo = (const float*)d_in[4];
  float* out = (float*)d_out;

  char* ws = (char*)d_ws;
  unsigned short* xb   = (unsigned short*)(ws + 0);          // 16 MiB: x bf16 [8192,1024]
  unsigned short* wT   = (unsigned short*)(ws + 16777216);   //  6 MiB: [3,H,D,E] bf16
  unsigned short* woT  = (unsigned short*)(ws + 23068672);   //  2 MiB: [E,HD] bf16
  unsigned short* qb   = (unsigned short*)(ws + 25165824);   // 16 MiB: q [B,H,T,D] (pre-scaled)
  unsigned short* kb   = (unsigned short*)(ws + 41943040);   // 16 MiB: k [B,H,T,D]
  unsigned short* vTb  = (unsigned short*)(ws + 58720256);   // 16 MiB: v^T [B,H,D,T]
  unsigned short* aob  = (unsigned short*)(ws + 75497472);   // 16 MiB: attn out [B,T,H,D]
  // total: 92,274,688 bytes

  prep_k<<<dim3(3072), dim3(256), 0, stream>>>(x, Wq, Wk, Wv, Wo, xb, wT, woT);
  qkv_gemm_k<<<dim3(BT_ / 128, 3072 / 128), dim3(256), 0, stream>>>(xb, wT, qb, kb, vTb);
  attn_k<<<dim3(512), dim3(256), 0, stream>>>(qb, kb, vTb, aob);
  proj_k<<<dim3(BT_ / 128, E_ / 128), dim3(256), 0, stream>>>(aob, woT, out);
}